// Round 15
// baseline (403.136 us; speedup 1.0000x reference)
//
#include <hip/hip_runtime.h>
#include <math.h>

// Problem constants
#define BATCH 16
#define HH 1024
#define WW 1024
#define TSTR 72          // padded LDS row stride (no pow2 stride)
#define NBLK 4096        // 16 images * 16x16 tiles of 64x64
#define NB0 1024         // pass0 blocks (64 per image)
#define NTOT 16777216.0  // 16*1024*1024

__device__ __forceinline__ float sigmf(float x) { return 1.0f / (1.0f + __expf(-x)); }

__device__ __forceinline__ double wredd(double v) {
#pragma unroll
    for (int o = 32; o; o >>= 1) v += __shfl_down(v, o, 64);
    return v;
}
__device__ __forceinline__ float wredminf(float v) {
#pragma unroll
    for (int o = 32; o; o >>= 1) v = fminf(v, __shfl_down(v, o, 64));
    return v;
}
__device__ __forceinline__ float wredmaxf(float v) {
#pragma unroll
    for (int o = 32; o; o >>= 1) v = fmaxf(v, __shfl_down(v, o, 64));
    return v;
}

// ---------------------------------------------------------------------------
// Pass 0: stream dem, per-image sum / sumsq partials (float4 loads).
// Block b: image b>>6, chunk b&63. Partials consumed by pass1's prologue
// (reduce0 kernel eliminated — it was a 1-wave serial kernel).
// ---------------------------------------------------------------------------
__global__ __launch_bounds__(256) void pass0_kernel(
    const float* __restrict__ dem, double* __restrict__ pD0)
{
    const int blk = blockIdx.x;
    const int tid = threadIdx.x;
    const float4* __restrict__ p =
        (const float4*)(dem + (size_t)blk * 16384);
    double s = 0.0, ss = 0.0;
    for (int i = tid; i < 4096; i += 256) {
        float4 v = p[i];
        s  += (double)v.x + (double)v.y + (double)v.z + (double)v.w;
        ss += (double)v.x * v.x + (double)v.y * v.y
            + (double)v.z * v.z + (double)v.w * v.w;
    }
    s = wredd(s); ss = wredd(ss);
    __shared__ double sh[2][4];
    const int lane = tid & 63, w = tid >> 6;
    if (lane == 0) { sh[0][w] = s; sh[1][w] = ss; }
    __syncthreads();
    if (tid == 0) {
        pD0[blk]        = sh[0][0] + sh[0][1] + sh[0][2] + sh[0][3];
        pD0[NB0 + blk]  = sh[1][0] + sh[1][1] + sh[1][2] + sh[1][3];
    }
}

// ---------------------------------------------------------------------------
// Pass 1 (r13 verified: 213 us, 60 VGPR, 41% occ, VALUBusy 62%).
// Unchanged except PROLOGUE: wave 0 reduces this image's 64 (sum,sumsq)
// partials from pD0 -> mean, 1/(std+eps) in LDS, overlapped with the other
// waves' stage-A staging. Replaces the former reduce0 kernel.
// ---------------------------------------------------------------------------
__global__ __launch_bounds__(256, 4) void pass1_kernel(
    const float* __restrict__ pred, const float* __restrict__ target,
    const float* __restrict__ dem, const double* __restrict__ pD0,
    double* __restrict__ pD1, float* __restrict__ pF1)
{
    const int blk = blockIdx.x;
    const int img = blk >> 8;
    const int tile = blk & 255;
    const int tly = (tile >> 4) << 6;
    const int tlx = (tile & 15) << 6;
    const size_t ioff = (size_t)img * (size_t)(HH * WW);
    const float* __restrict__ tg = target + ioff;
    const float* __restrict__ pr = pred + ioff;
    const float* __restrict__ dm = dem + ioff;

    __shared__ union {
        struct {
            float t[70 * TSTR];          // target, halo 3 (20160 B)
            unsigned char e[68 * TSTR];  // edges, halo 2
            unsigned char d[66 * TSTR];  // dilated, halo 1
        } a;                             // 29808 B
        struct {
            float p[66 * TSTR];          // sigmoid(pred), halo 1 (19008 B)
            float d[66 * TSTR];          // dem, halo 1 (19008 B)
        } b;                             // 38016 B
    } sm;
    __shared__ double sD[9][4];
    __shared__ float sF[4][4];
    __shared__ float sStat[2];           // [0]=hmean, [1]=histd

    const int tid = threadIdx.x;
    const int tx = tid & 63;
    const int ty4 = tid >> 6;

    // ---- Prologue (wave 0): per-image dem stats from pass0 partials.
    // Written before the first __syncthreads(); consumed in stage B.
    if (tid < 64) {
        double s  = pD0[img * 64 + tid];
        double ss = pD0[NB0 + img * 64 + tid];
        s = wredd(s); ss = wredd(ss);
        if (tid == 0) {
            const double NPI = 1048576.0;
            double mean = s / NPI;
            double var = (ss - s * s / NPI) / (NPI - 1.0);
            if (var < 0.0) var = 0.0;
            sStat[0] = (float)mean;
            sStat[1] = (float)(1.0 / (sqrt(var) + 1e-8));
        }
    }

    // ---- Stage A: target halo 3 (zero padded)
    for (int i = tid; i < 70 * 70; i += 256) {
        int r = i / 70, c = i - r * 70;
        int gy = tly - 3 + r, gx = tlx - 3 + c;
        float v = 0.0f;
        if ((unsigned)gy < HH && (unsigned)gx < WW) v = tg[gy * WW + gx];
        sm.a.t[r * TSTR + c] = v;
    }
    __syncthreads();
    // edges at halo 2
    for (int i = tid; i < 68 * 68; i += 256) {
        int r = i / 68, c = i - r * 68;
        int gy = tly - 2 + r, gx = tlx - 2 + c;
        unsigned char ev = 0;
        if ((unsigned)gy < HH && (unsigned)gx < WW) {
            float s = 0.0f;
#pragma unroll
            for (int dy = 0; dy < 3; dy++)
#pragma unroll
                for (int dx = 0; dx < 3; dx++)
                    s += sm.a.t[(r + dy) * TSTR + (c + dx)];
            s *= (1.0f / 9.0f);
            float cen = sm.a.t[(r + 1) * TSTR + (c + 1)];
            ev = (fabsf(cen - s) > 0.15f) ? 1 : 0;
        }
        sm.a.e[r * TSTR + c] = ev;
    }
    __syncthreads();
    // dilated at halo 1
    for (int i = tid; i < 66 * 66; i += 256) {
        int r = i / 66, c = i - r * 66;
        int gy = tly - 1 + r, gx = tlx - 1 + c;
        unsigned char dv = 0;
        if ((unsigned)gy < HH && (unsigned)gx < WW) {
            int s = 0;
#pragma unroll
            for (int dy = 0; dy < 3; dy++)
#pragma unroll
                for (int dx = 0; dx < 3; dx++)
                    s += sm.a.e[(r + dy) * TSTR + (c + dx)];
            dv = (s > 0) ? 1 : 0;
        }
        sm.a.d[r * TSTR + c] = dv;
    }
    __syncthreads();
    // interior: eroded + bce1 + bce2 (f32 accumulation)
    float a1 = 0.0f, a2 = 0.0f;
#pragma unroll 4
    for (int i = 0; i < 16; i++) {
        int iy = ty4 + 4 * i;
        int gy = tly + iy, gx = tlx + tx;
        int s = 0;
#pragma unroll
        for (int dy = 0; dy < 3; dy++)
#pragma unroll
            for (int dx = 0; dx < 3; dx++)
                s += sm.a.d[(iy + dy) * TSTR + (tx + dx)];
        float te = (s == 9) ? 1.0f : 0.0f;
        float tv = sm.a.t[(iy + 3) * TSTR + (tx + 3)];
        float x = pr[gy * WW + gx];
        float L = __logf(1.0f + __expf(-fabsf(x)));
        float mx = fmaxf(x, 0.0f);
        a1 += mx - x * tv + L;
        a2 += mx - x * te + L;
    }
    __syncthreads();

    // ---- Stage B: stage sigmoid(pred) AND dem (halo 1) together
    for (int i = tid; i < 66 * 66; i += 256) {
        int r = i / 66, c = i - r * 66;
        int gy = tly - 1 + r, gx = tlx - 1 + c;
        float vp = 0.0f, vd = 0.0f;
        if ((unsigned)gy < HH && (unsigned)gx < WW) {
            int idx = gy * WW + gx;
            vp = sigmf(pr[idx]);
            vd = dm[idx];
        }
        sm.b.p[r * TSTR + c] = vp;
        sm.b.d[r * TSTR + c] = vd;
    }
    __syncthreads();
    const float hmean = sStat[0];
    const float histd = sStat[1];

    float gpmin = 3.4e38f, gpmax = 0.0f, gdmin = 3.4e38f, gdmax = 0.0f;
    float aSp = 0.0f, aSpp = 0.0f, aSd = 0.0f, aSdd = 0.0f, aSpd = 0.0f;
    float a_cc = 0.0f, a_hc = 0.0f;
#pragma unroll 4
    for (int i = 0; i < 16; i++) {
        int iy = ty4 + 4 * i;
        const float* bp = &sm.b.p[iy * TSTR + tx];
        const float* bd = &sm.b.d[iy * TSTR + tx];
        // Sobel on sigmoid(pred)
        float p00 = bp[0], p01 = bp[1], p02 = bp[2];
        float p10 = bp[TSTR], p11 = bp[TSTR + 1], p12 = bp[TSTR + 2];
        float p20 = bp[2 * TSTR], p21 = bp[2 * TSTR + 1], p22 = bp[2 * TSTR + 2];
        float gxv = (p02 - p00) + 2.0f * (p12 - p10) + (p22 - p20);
        float gyv = (p20 - p00) + 2.0f * (p21 - p01) + (p22 - p02);
        float gp = sqrtf(gxv * gxv + gyv * gyv + 1e-8f);
        gpmin = fminf(gpmin, gp);
        gpmax = fmaxf(gpmax, gp);
        aSp += gp; aSpp += gp * gp;
        // Sobel + Laplacian on dem
        float d00 = bd[0], d01 = bd[1], d02 = bd[2];
        float d10 = bd[TSTR], d11 = bd[TSTR + 1], d12 = bd[TSTR + 2];
        float d20 = bd[2 * TSTR], d21 = bd[2 * TSTR + 1], d22 = bd[2 * TSTR + 2];
        float hxv = (d02 - d00) + 2.0f * (d12 - d10) + (d22 - d20);
        float hyv = (d20 - d00) + 2.0f * (d21 - d01) + (d22 - d02);
        float gd = sqrtf(hxv * hxv + hyv * hyv + 1e-8f);
        gdmin = fminf(gdmin, gd);
        gdmax = fmaxf(gdmax, gd);
        aSd += gd; aSdd += gd * gd; aSpd += gp * gd;
        // curvature: sigmoid(tanh(lap*0.1)*10), tanh via exp
        float lap = d01 + d10 + d12 + d21 - 4.0f * d11;
        float e2 = __expf(0.2f * lap);
        float th = (e2 - 1.0f) / (e2 + 1.0f);
        float score = 1.0f / (1.0f + __expf(-10.0f * th));
        a_cc += p11 * score;
        // height norm
        float z = (d11 - hmean) * histd;
        a_hc += p11 * __expf(-0.5f * z * z);
    }

    // ---- block reduce partials (widen to f64 at reduction boundary)
    double r0 = wredd((double)a1), r1 = wredd((double)a2);
    double r2 = wredd((double)a_cc), r3 = wredd((double)a_hc);
    double r4 = wredd((double)aSp), r5 = wredd((double)aSpp);
    double r6 = wredd((double)aSd), r7 = wredd((double)aSdd);
    double r8 = wredd((double)aSpd);
    float f0 = wredminf(gpmin), f1 = wredmaxf(gpmax);
    float f2 = wredminf(gdmin), f3 = wredmaxf(gdmax);
    const int lane = tid & 63, w = tid >> 6;
    if (lane == 0) {
        sD[0][w] = r0; sD[1][w] = r1; sD[2][w] = r2; sD[3][w] = r3;
        sD[4][w] = r4; sD[5][w] = r5; sD[6][w] = r6; sD[7][w] = r7;
        sD[8][w] = r8;
        sF[0][w] = f0; sF[1][w] = f1; sF[2][w] = f2; sF[3][w] = f3;
    }
    __syncthreads();
    if (tid == 0) {
#pragma unroll
        for (int q = 0; q < 9; q++)
            pD1[q * NBLK + blk] = sD[q][0] + sD[q][1] + sD[q][2] + sD[q][3];
        pF1[0 * NBLK + blk] = fminf(fminf(sF[0][0], sF[0][1]), fminf(sF[0][2], sF[0][3]));
        pF1[1 * NBLK + blk] = fmaxf(fmaxf(sF[1][0], sF[1][1]), fmaxf(sF[1][2], sF[1][3]));
        pF1[2 * NBLK + blk] = fminf(fminf(sF[2][0], sF[2][1]), fminf(sF[2][2], sF[2][3]));
        pF1[3 * NBLK + blk] = fmaxf(fmaxf(sF[3][0], sF[3][1]), fmaxf(sF[3][2], sF[3][3]));
    }
}

// ---------------------------------------------------------------------------
// Final (wave-parallel): waves 0-2 reduce 3 f64 sums each (9 serial wredd
// chains -> 3), wave 3 does the 4 min/max. Then closed-form combine.
// ---------------------------------------------------------------------------
__global__ __launch_bounds__(256) void final_kernel(
    const double* __restrict__ pD1, const float* __restrict__ pF1,
    float* __restrict__ out)
{
    const int tid = threadIdx.x;
    const int lane = tid & 63, w = tid >> 6;
    __shared__ double sd[9];
    __shared__ float sf[4];

    if (w < 3) {
#pragma unroll
        for (int k = 0; k < 3; k++) {
            int q = w * 3 + k;
            double s = 0.0;
            for (int i = lane; i < NBLK; i += 64) s += pD1[q * NBLK + i];
            s = wredd(s);
            if (lane == 0) sd[q] = s;
        }
    } else {
        float m0 = 3.4e38f, m1 = 0.0f, m2 = 3.4e38f, m3 = 0.0f;
        for (int i = lane; i < NBLK; i += 64) {
            m0 = fminf(m0, pF1[0 * NBLK + i]);
            m1 = fmaxf(m1, pF1[1 * NBLK + i]);
            m2 = fminf(m2, pF1[2 * NBLK + i]);
            m3 = fmaxf(m3, pF1[3 * NBLK + i]);
        }
        m0 = wredminf(m0); m1 = wredmaxf(m1); m2 = wredminf(m2); m3 = wredmaxf(m3);
        if (lane == 0) { sf[0] = m0; sf[1] = m1; sf[2] = m2; sf[3] = m3; }
    }
    __syncthreads();
    if (tid == 0) {
        float gpmin = sf[0], gpmax = sf[1], gdmin = sf[2], gdmax = sf[3];

        const double N = NTOT;
        double bce1 = sd[0] / N;
        double bce2 = sd[1] / N;
        double cc   = sd[2] / N;
        double hc   = sd[3] / N;

        // grad consistency from moments: d = Ap*gp + Bp - (Ad*gd + Bd)
        double Ap, Bp, Ad, Bd;
        if (gpmax > gpmin) {
            Ap = 1.0 / ((double)gpmax - (double)gpmin + 1e-8);
            Bp = -(double)gpmin * Ap;
        } else { Ap = 1.0; Bp = 0.0; }
        if (gdmax > gdmin) {
            Ad = 1.0 / ((double)gdmax - (double)gdmin + 1e-8);
            Bd = -(double)gdmin * Ad;
        } else { Ad = 1.0; Bd = 0.0; }
        double C = Bp - Bd;
        // sd[4]=S_p sd[5]=S_pp sd[6]=S_d sd[7]=S_dd sd[8]=S_pd
        double sum_d2 = Ap * Ap * sd[5] + Ad * Ad * sd[7] + N * C * C
                      - 2.0 * Ap * Ad * sd[8]
                      + 2.0 * Ap * C * sd[4]
                      - 2.0 * Ad * C * sd[6];
        double gc = sum_d2 / N;

        double total = 0.8 * bce1 + 0.1 * bce2 + 0.1 * (gc - 0.5 * hc - 0.3 * cc);
        out[0] = (float)total;
    }
}

extern "C" void kernel_launch(void* const* d_in, const int* in_sizes, int n_in,
                              void* d_out, int out_size, void* d_ws, size_t ws_size,
                              hipStream_t stream)
{
    (void)in_sizes; (void)n_in; (void)out_size; (void)ws_size;
    const float* pred = (const float*)d_in[0];
    const float* target = (const float*)d_in[1];
    const float* dem = (const float*)d_in[2];
    float* out = (float*)d_out;

    // ws layout (every slot written before read each call; poison-safe):
    //   pD0 : 2*NB0 doubles   (pass0 per-image sum/sumsq partials)
    //   pD1 : 9*NBLK doubles  (pass1 partials)
    //   pF1 : 4*NBLK floats   (pass1 min/max partials)
    double* pD0 = (double*)d_ws;
    double* pD1 = pD0 + 2 * NB0;
    float*  pF1 = (float*)(pD1 + 9 * NBLK);

    pass0_kernel<<<NB0, 256, 0, stream>>>(dem, pD0);
    pass1_kernel<<<NBLK, 256, 0, stream>>>(pred, target, dem, pD0, pD1, pF1);
    final_kernel<<<1, 256, 0, stream>>>(pD1, pF1, out);
}